// Round 1
// baseline (1162.220 us; speedup 1.0000x reference)
//
#include <hip/hip_runtime.h>

#define V1n 40962
#define V2n 163842
#define Bn  4

typedef _Float16 h8   __attribute__((ext_vector_type(8)));
typedef float    f32x4 __attribute__((ext_vector_type(4)));

__device__ __forceinline__ float h2f(_Float16 h) { return (float)h; }

// ---------------- K1: upconv GEMM  raw[b][v][j] = sum_c x1[b][c][v]*Wup[j][c] + bup[j]  (fp16 out)
__global__ __launch_bounds__(256) void k_upconv(const float* __restrict__ x1,
    const float* __restrict__ Wup, const float* __restrict__ bup,
    _Float16* __restrict__ rawq) {
  int b = blockIdx.y;
  int v = blockIdx.x * 64 + (threadIdx.x & 63);
  int j0 = __builtin_amdgcn_readfirstlane(((int)threadIdx.x >> 6) * 56);
  int vc = min(v, V1n - 1);
  float acc[56];
#pragma unroll
  for (int jj = 0; jj < 56; ++jj) acc[jj] = bup[j0 + jj];
  const float* xb = x1 + (size_t)b * 64 * V1n + vc;
#pragma unroll
  for (int cb = 0; cb < 64; cb += 16) {
    float xv[16];
#pragma unroll
    for (int cc = 0; cc < 16; ++cc) xv[cc] = xb[(size_t)(cb + cc) * V1n];
#pragma unroll
    for (int jj = 0; jj < 56; ++jj) {
      const float* wr = Wup + (size_t)(j0 + jj) * 64 + cb;
#pragma unroll
      for (int cc = 0; cc < 16; ++cc) acc[jj] = fmaf(xv[cc], wr[cc], acc[jj]);
    }
  }
  if (v < V1n) {
    _Float16* dst = rawq + ((size_t)b * V1n + v) * 224 + j0;
#pragma unroll
    for (int g = 0; g < 7; ++g) {
      h8 pk;
#pragma unroll
      for (int e = 0; e < 8; ++e) pk[e] = (_Float16)acc[g * 8 + e];
      *(h8*)(dst + g * 8) = pk;
    }
  }
}

// ---------------- K2: assemble y[b][v][0:32]=upconv-scatter, [32:64]=x2^T   (fp16, row = MFMA feed)
__global__ __launch_bounds__(256) void k_assemble(const float* __restrict__ x2,
    const int* __restrict__ top, const int* __restrict__ down,
    const _Float16* __restrict__ rawq, _Float16* __restrict__ y) {
  int b = blockIdx.y;
  int v = blockIdx.x * 256 + threadIdx.x;
  if (v >= V2n) return;
  const _Float16* rb = rawq + (size_t)b * V1n * 224;
  h8 r0, r1, r2, r3;
  if (v < V1n) {
    int f = top[v];
    const _Float16* src = rb + (size_t)(f / 7) * 224 + (f % 7) * 32;
    r0 = *(const h8*)src;        r1 = *(const h8*)(src + 8);
    r2 = *(const h8*)(src + 16); r3 = *(const h8*)(src + 24);
  } else {
    int k = v - V1n;
    int d0 = down[2 * k], d1 = down[2 * k + 1];
    const _Float16* se = rb + (size_t)(d0 / 7) * 224 + (d0 % 7) * 32;
    const _Float16* so = rb + (size_t)(d1 / 7) * 224 + (d1 % 7) * 32;
    h8 a0 = *(const h8*)se,        a1 = *(const h8*)(se + 8);
    h8 a2 = *(const h8*)(se + 16), a3 = *(const h8*)(se + 24);
    h8 c0 = *(const h8*)so,        c1 = *(const h8*)(so + 8);
    h8 c2 = *(const h8*)(so + 16), c3 = *(const h8*)(so + 24);
#pragma unroll
    for (int i = 0; i < 4; ++i) {
      // torch view semantics: out ch o<16 pairs (2o,2o+1) of even row; o>=16 of odd row
      r0[i]     = (_Float16)(0.5f * (h2f(a0[2 * i]) + h2f(a0[2 * i + 1])));
      r0[4 + i] = (_Float16)(0.5f * (h2f(a1[2 * i]) + h2f(a1[2 * i + 1])));
      r1[i]     = (_Float16)(0.5f * (h2f(a2[2 * i]) + h2f(a2[2 * i + 1])));
      r1[4 + i] = (_Float16)(0.5f * (h2f(a3[2 * i]) + h2f(a3[2 * i + 1])));
      r2[i]     = (_Float16)(0.5f * (h2f(c0[2 * i]) + h2f(c0[2 * i + 1])));
      r2[4 + i] = (_Float16)(0.5f * (h2f(c1[2 * i]) + h2f(c1[2 * i + 1])));
      r3[i]     = (_Float16)(0.5f * (h2f(c2[2 * i]) + h2f(c2[2 * i + 1])));
      r3[4 + i] = (_Float16)(0.5f * (h2f(c3[2 * i]) + h2f(c3[2 * i + 1])));
    }
  }
  _Float16* dst = y + ((size_t)b * V2n + v) * 64;
  *(h8*)(dst)      = r0; *(h8*)(dst + 8)  = r1;
  *(h8*)(dst + 16) = r2; *(h8*)(dst + 24) = r3;
  const float* xp = x2 + (size_t)b * 32 * V2n + v;
#pragma unroll
  for (int g2 = 0; g2 < 4; ++g2) {
    h8 px;
#pragma unroll
    for (int e = 0; e < 8; ++e) px[e] = (_Float16)xp[(size_t)(g2 * 8 + e) * V2n];
    *(h8*)(dst + 32 + g2 * 8) = px;
  }
}

// B-operand fragment: lane holds B[k=quad*8+j][n=lane&15] = W[n][k..k+7] (W is (N,K) row-major)
__device__ __forceinline__ h8 w_frag(const float* __restrict__ p) {
  float4 w0 = *(const float4*)p;
  float4 w1 = *(const float4*)(p + 4);
  h8 f;
  f[0] = (_Float16)w0.x; f[1] = (_Float16)w0.y; f[2] = (_Float16)w0.z; f[3] = (_Float16)w0.w;
  f[4] = (_Float16)w1.x; f[5] = (_Float16)w1.y; f[6] = (_Float16)w1.z; f[7] = (_Float16)w1.w;
  return f;
}

// ---------------- K3: conv1  t1[v][o] = sum_{j,c} y[neigh[7v+j]][c] * W1[o][j*64+c]   (pre-BN, fp16)
__global__ __launch_bounds__(256) void k_conv1(const _Float16* __restrict__ y,
    const int* __restrict__ neigh, const float* __restrict__ W1,
    _Float16* __restrict__ t1) {
  int b = blockIdx.y;
  int lane = threadIdx.x & 63, wv = threadIdx.x >> 6;
  int col = lane & 15, quad = lane >> 4;
  int v0 = blockIdx.x * 64 + wv * 16;
  int v = v0 + col;
  int vc = min(v, V2n - 1);
  const _Float16* yb = y + (size_t)b * V2n * 64;
  f32x4 acc0 = {0.f, 0.f, 0.f, 0.f}, acc1 = {0.f, 0.f, 0.f, 0.f};
#pragma unroll
  for (int kt = 0; kt < 14; ++kt) {
    int j = kt >> 1;
    int c = (kt & 1) * 32 + quad * 8;
    int idx = neigh[7 * vc + j];
    h8 a = *(const h8*)(yb + (size_t)idx * 64 + c);
    int ko = kt * 32 + quad * 8;
    h8 b0 = w_frag(W1 + (size_t)col * 448 + ko);
    h8 b1 = w_frag(W1 + (size_t)(16 + col) * 448 + ko);
    acc0 = __builtin_amdgcn_mfma_f32_16x16x32_f16(a, b0, acc0, 0, 0, 0);
    acc1 = __builtin_amdgcn_mfma_f32_16x16x32_f16(a, b1, acc1, 0, 0, 0);
  }
  // C/D: row(v) = quad*4+r, col(o) = lane&15 -> transpose via LDS for coalesced (v,o) stores
  __shared__ _Float16 tile[4][16][32];
#pragma unroll
  for (int r = 0; r < 4; ++r) {
    tile[wv][quad * 4 + r][col]      = (_Float16)acc0[r];
    tile[wv][quad * 4 + r][16 + col] = (_Float16)acc1[r];
  }
  __syncthreads();
  int row = threadIdx.x >> 2, ch = threadIdx.x & 3;
  int vv = blockIdx.x * 64 + row;
  if (vv < V2n) {
    h8 val = *(const h8*)&tile[row >> 4][row & 15][ch * 8];
    *(h8*)(t1 + ((size_t)b * V2n + vv) * 32 + ch * 8) = val;
  }
}

// ---------------- K4: per-(b,ch) sum/sumsq over fp16 t1
__global__ __launch_bounds__(256) void k_stats_h(const _Float16* __restrict__ t1,
                                                 float* __restrict__ sums) {
  int b = blockIdx.y, i = blockIdx.x;            // i in [0,32)
  int o = threadIdx.x & 31, w = threadIdx.x >> 5; // w in [0,8)
  const _Float16* tb = t1 + (size_t)b * V2n * 32;
  float s = 0.f, q = 0.f;
  for (int v = i * 8 + w; v < V2n; v += 256) {
    float x = h2f(tb[(size_t)v * 32 + o]);
    s += x; q += x * x;
  }
  __shared__ float ls[8][32], lq[8][32];
  ls[w][o] = s; lq[w][o] = q;
  __syncthreads();
  if (w == 0) {
#pragma unroll
    for (int k = 1; k < 8; ++k) { s += ls[k][o]; q += lq[k][o]; }
    atomicAdd(&sums[b * 32 + o], s);
    atomicAdd(&sums[128 + b * 32 + o], q);
  }
}

// ---------------- finalize: scale = g*rsqrt(var+eps), shift = be - mu*scale
__global__ void k_finalize(const float* __restrict__ sums, const float* __restrict__ g,
                           const float* __restrict__ be, float* __restrict__ sc,
                           float* __restrict__ sh) {
  int i = threadIdx.x;
  if (i >= 128) return;
  float inv = 1.0f / (float)V2n;
  float mu = sums[i] * inv;
  float var = fmaf(sums[128 + i], inv, -mu * mu);
  float rs = rsqrtf(var + 1e-5f);
  int o = i & 31;
  float scale = rs * g[o];
  sc[i] = scale;
  sh[i] = fmaf(-mu, scale, be[o]);
}

// ---------------- K5: conv2 with fused BN1+LeakyReLU on the gathered A; pre-BN2 -> d_out (B,32,V2)
__global__ __launch_bounds__(256) void k_conv2(const _Float16* __restrict__ t1,
    const int* __restrict__ neigh, const float* __restrict__ W2,
    const float* __restrict__ sc1, const float* __restrict__ sh1,
    float* __restrict__ out) {
  int b = blockIdx.y;
  int lane = threadIdx.x & 63, wv = threadIdx.x >> 6;
  int col = lane & 15, quad = lane >> 4;
  int v0 = blockIdx.x * 64 + wv * 16;
  int v = v0 + col;
  int vc = min(v, V2n - 1);
  float sc[8], sh[8];
#pragma unroll
  for (int i = 0; i < 8; ++i) {
    sc[i] = sc1[b * 32 + quad * 8 + i];
    sh[i] = sh1[b * 32 + quad * 8 + i];
  }
  const _Float16* tb = t1 + (size_t)b * V2n * 32;
  f32x4 acc0 = {0.f, 0.f, 0.f, 0.f}, acc1 = {0.f, 0.f, 0.f, 0.f};
#pragma unroll
  for (int j = 0; j < 7; ++j) {
    int idx = neigh[7 * vc + j];
    h8 raw = *(const h8*)(tb + (size_t)idx * 32 + quad * 8);
    h8 a;
#pragma unroll
    for (int e = 0; e < 8; ++e) {
      float f = fmaf(h2f(raw[e]), sc[e], sh[e]);
      f = fmaxf(f, 0.2f * f);             // LeakyReLU(0.2)
      a[e] = (_Float16)f;
    }
    int ko = j * 32 + quad * 8;
    h8 b0 = w_frag(W2 + (size_t)col * 224 + ko);
    h8 b1 = w_frag(W2 + (size_t)(16 + col) * 224 + ko);
    acc0 = __builtin_amdgcn_mfma_f32_16x16x32_f16(a, b0, acc0, 0, 0, 0);
    acc1 = __builtin_amdgcn_mfma_f32_16x16x32_f16(a, b1, acc1, 0, 0, 0);
  }
  float* ob = out + (size_t)b * 32 * V2n;
  int vrow = v0 + quad * 4;
  if (blockIdx.x != gridDim.x - 1) {
    float* p0 = ob + (size_t)col * V2n + vrow;          // V2 % 4 == 2 -> only 8B aligned
    *(float2*)p0       = make_float2(acc0[0], acc0[1]);
    *(float2*)(p0 + 2) = make_float2(acc0[2], acc0[3]);
    float* p1 = ob + (size_t)(16 + col) * V2n + vrow;
    *(float2*)p1       = make_float2(acc1[0], acc1[1]);
    *(float2*)(p1 + 2) = make_float2(acc1[2], acc1[3]);
  } else {
#pragma unroll
    for (int r = 0; r < 4; ++r) {
      if (vrow + r < V2n) {
        ob[(size_t)col * V2n + vrow + r]        = acc0[r];
        ob[(size_t)(16 + col) * V2n + vrow + r] = acc1[r];
      }
    }
  }
}

// ---------------- K6: per-(b,ch) stats over fp32 d_out rows
__global__ __launch_bounds__(256) void k_stats_f32(const float* __restrict__ out,
                                                   float* __restrict__ sums) {
  int row = blockIdx.y;       // b*32+o
  int qrt = blockIdx.x;       // 0..3
  const float* p = out + (size_t)row * V2n;
  int i0 = qrt * 20480;
  int iend = (qrt == 3) ? 81921 : i0 + 20480;   // float2 granularity, V2/2 = 81921
  float s = 0.f, q = 0.f;
  for (int i = i0 + (int)threadIdx.x; i < iend; i += 256) {
    float2 x = *(const float2*)(p + 2 * (size_t)i);
    s += x.x + x.y;
    q += x.x * x.x + x.y * x.y;
  }
  __shared__ float rs[256], rq[256];
  int t = threadIdx.x;
  rs[t] = s; rq[t] = q;
  __syncthreads();
  for (int k = 128; k > 0; k >>= 1) {
    if (t < k) { rs[t] += rs[t + k]; rq[t] += rq[t + k]; }
    __syncthreads();
  }
  if (t == 0) {
    atomicAdd(&sums[row], rs[0]);
    atomicAdd(&sums[128 + row], rq[0]);
  }
}

// ---------------- K7: in-place BN2 + LeakyReLU on d_out
__global__ __launch_bounds__(256) void k_bnorm(float* __restrict__ out,
    const float* __restrict__ sc, const float* __restrict__ sh) {
  int row = blockIdx.y, qrt = blockIdx.x;
  float scale = sc[row], shift = sh[row];
  float* p = out + (size_t)row * V2n;
  int i0 = qrt * 20480;
  int iend = (qrt == 3) ? 81921 : i0 + 20480;
  for (int i = i0 + (int)threadIdx.x; i < iend; i += 256) {
    float2 x = *(float2*)(p + 2 * (size_t)i);
    float a = fmaf(x.x, scale, shift); a = fmaxf(a, 0.2f * a);
    float b = fmaf(x.y, scale, shift); b = fmaxf(b, 0.2f * b);
    *(float2*)(p + 2 * (size_t)i) = make_float2(a, b);
  }
}

extern "C" void kernel_launch(void* const* d_in, const int* in_sizes, int n_in,
                              void* d_out, int out_size, void* d_ws, size_t ws_size,
                              hipStream_t stream) {
  const float* x1   = (const float*)d_in[0];
  const float* x2   = (const float*)d_in[1];
  const int*   neigh= (const int*)d_in[2];
  const int*   top  = (const int*)d_in[3];
  const int*   down = (const int*)d_in[4];
  const float* Wup  = (const float*)d_in[5];
  const float* bup  = (const float*)d_in[6];
  const float* W1   = (const float*)d_in[7];
  // d_in[8] = b1: constant per-channel shift, cancels exactly in BN -> skipped
  const float* g1   = (const float*)d_in[9];
  const float* be1  = (const float*)d_in[10];
  const float* W2   = (const float*)d_in[11];
  // d_in[12] = b2: cancels in BN -> skipped
  const float* g2   = (const float*)d_in[13];
  const float* be2  = (const float*)d_in[14];
  float* out = (float*)d_out;

  char* ws = (char*)d_ws;
  _Float16* rawq = (_Float16*)ws;                         //  73,403,904 B
  _Float16* y    = (_Float16*)(ws + 73403904);            //  83,887,104 B
  _Float16* t1   = (_Float16*)(ws + 157291008);           //  41,943,552 B
  float* stats   = (float*)(ws + 199234560);              //   4 KiB
  float* sums1 = stats;        float* sums2 = stats + 256;
  float* sc1   = stats + 512;  float* sh1   = stats + 640;
  float* sc2   = stats + 768;  float* sh2   = stats + 896;

  hipMemsetAsync(sums1, 0, 512 * sizeof(float), stream);

  k_upconv   <<<dim3(641, Bn),  256, 0, stream>>>(x1, Wup, bup, rawq);
  k_assemble <<<dim3(641, Bn),  256, 0, stream>>>(x2, top, down, rawq, y);
  k_conv1    <<<dim3(2561, Bn), 256, 0, stream>>>(y, neigh, W1, t1);
  k_stats_h  <<<dim3(32, Bn),   256, 0, stream>>>(t1, sums1);
  k_finalize <<<1, 128, 0, stream>>>(sums1, g1, be1, sc1, sh1);
  k_conv2    <<<dim3(2561, Bn), 256, 0, stream>>>(t1, neigh, W2, sc1, sh1, out);
  k_stats_f32<<<dim3(4, 128),   256, 0, stream>>>(out, sums2);
  k_finalize <<<1, 128, 0, stream>>>(sums2, g2, be2, sc2, sh2);
  k_bnorm    <<<dim3(4, 128),   256, 0, stream>>>(out, sc2, sh2);
}

// Round 2
// 877.125 us; speedup vs baseline: 1.3250x; 1.3250x over previous
//
#include <hip/hip_runtime.h>

#define V1n 40962
#define V2n 163842
#define Bn  4

typedef _Float16 h8   __attribute__((ext_vector_type(8)));
typedef float    f32x4 __attribute__((ext_vector_type(4)));

__device__ __forceinline__ float h2f(_Float16 h) { return (float)h; }

// ---------------- K1: upconv GEMM  raw[b][v][j] = sum_c x1[b][c][v]*Wup[j][c] + bup[j]  (fp16 out)
__global__ __launch_bounds__(256) void k_upconv(const float* __restrict__ x1,
    const float* __restrict__ Wup, const float* __restrict__ bup,
    _Float16* __restrict__ rawq) {
  int b = blockIdx.y;
  int v = blockIdx.x * 64 + (threadIdx.x & 63);
  int j0 = __builtin_amdgcn_readfirstlane(((int)threadIdx.x >> 6) * 56);
  int vc = min(v, V1n - 1);
  float acc[56];
#pragma unroll
  for (int jj = 0; jj < 56; ++jj) acc[jj] = bup[j0 + jj];
  const float* xb = x1 + (size_t)b * 64 * V1n + vc;
#pragma unroll
  for (int cb = 0; cb < 64; cb += 16) {
    float xv[16];
#pragma unroll
    for (int cc = 0; cc < 16; ++cc) xv[cc] = xb[(size_t)(cb + cc) * V1n];
#pragma unroll
    for (int jj = 0; jj < 56; ++jj) {
      const float* wr = Wup + (size_t)(j0 + jj) * 64 + cb;
#pragma unroll
      for (int cc = 0; cc < 16; ++cc) acc[jj] = fmaf(xv[cc], wr[cc], acc[jj]);
    }
  }
  if (v < V1n) {
    _Float16* dst = rawq + ((size_t)b * V1n + v) * 224 + j0;
#pragma unroll
    for (int g = 0; g < 7; ++g) {
      h8 pk;
#pragma unroll
      for (int e = 0; e < 8; ++e) pk[e] = (_Float16)acc[g * 8 + e];
      *(h8*)(dst + g * 8) = pk;
    }
  }
}

// ---------------- K2: assemble y[b][v][0:32]=upconv-scatter, [32:64]=x2^T   (fp16, row = MFMA feed)
__global__ __launch_bounds__(256) void k_assemble(const float* __restrict__ x2,
    const int* __restrict__ top, const int* __restrict__ down,
    const _Float16* __restrict__ rawq, _Float16* __restrict__ y) {
  int b = blockIdx.y;
  int v = blockIdx.x * 256 + threadIdx.x;
  if (v >= V2n) return;
  const _Float16* rb = rawq + (size_t)b * V1n * 224;
  h8 r0, r1, r2, r3;
  if (v < V1n) {
    int f = top[v];
    const _Float16* src = rb + (size_t)(f / 7) * 224 + (f % 7) * 32;
    r0 = *(const h8*)src;        r1 = *(const h8*)(src + 8);
    r2 = *(const h8*)(src + 16); r3 = *(const h8*)(src + 24);
  } else {
    int k = v - V1n;
    int d0 = down[2 * k], d1 = down[2 * k + 1];
    const _Float16* se = rb + (size_t)(d0 / 7) * 224 + (d0 % 7) * 32;
    const _Float16* so = rb + (size_t)(d1 / 7) * 224 + (d1 % 7) * 32;
    h8 a0 = *(const h8*)se,        a1 = *(const h8*)(se + 8);
    h8 a2 = *(const h8*)(se + 16), a3 = *(const h8*)(se + 24);
    h8 c0 = *(const h8*)so,        c1 = *(const h8*)(so + 8);
    h8 c2 = *(const h8*)(so + 16), c3 = *(const h8*)(so + 24);
#pragma unroll
    for (int i = 0; i < 4; ++i) {
      // torch view semantics: out ch o<16 pairs (2o,2o+1) of even row; o>=16 of odd row
      r0[i]     = (_Float16)(0.5f * (h2f(a0[2 * i]) + h2f(a0[2 * i + 1])));
      r0[4 + i] = (_Float16)(0.5f * (h2f(a1[2 * i]) + h2f(a1[2 * i + 1])));
      r1[i]     = (_Float16)(0.5f * (h2f(a2[2 * i]) + h2f(a2[2 * i + 1])));
      r1[4 + i] = (_Float16)(0.5f * (h2f(a3[2 * i]) + h2f(a3[2 * i + 1])));
      r2[i]     = (_Float16)(0.5f * (h2f(c0[2 * i]) + h2f(c0[2 * i + 1])));
      r2[4 + i] = (_Float16)(0.5f * (h2f(c1[2 * i]) + h2f(c1[2 * i + 1])));
      r3[i]     = (_Float16)(0.5f * (h2f(c2[2 * i]) + h2f(c2[2 * i + 1])));
      r3[4 + i] = (_Float16)(0.5f * (h2f(c3[2 * i]) + h2f(c3[2 * i + 1])));
    }
  }
  _Float16* dst = y + ((size_t)b * V2n + v) * 64;
  *(h8*)(dst)      = r0; *(h8*)(dst + 8)  = r1;
  *(h8*)(dst + 16) = r2; *(h8*)(dst + 24) = r3;
  const float* xp = x2 + (size_t)b * 32 * V2n + v;
#pragma unroll
  for (int g2 = 0; g2 < 4; ++g2) {
    h8 px;
#pragma unroll
    for (int e = 0; e < 8; ++e) px[e] = (_Float16)xp[(size_t)(g2 * 8 + e) * V2n];
    *(h8*)(dst + 32 + g2 * 8) = px;
  }
}

// ---------------- K2b: pack W1/W2 into fp16 MFMA B-fragment layout
// W1p[((kt*4+quad)*32 + o)*8 + e] = W1[o][kt*32+quad*8+e]   (kt<14)
// W2p likewise with kt<7, K=224
__global__ __launch_bounds__(256) void k_pack(const float* __restrict__ W1,
    const float* __restrict__ W2, _Float16* __restrict__ W1p,
    _Float16* __restrict__ W2p) {
  int i = blockIdx.x * 256 + threadIdx.x;
  if (i < 14336) {
    int e = i & 7, o = (i >> 3) & 31, g = i >> 8;       // g = kt*4+quad
    int k = (g >> 2) * 32 + (g & 3) * 8 + e;
    W1p[i] = (_Float16)W1[o * 448 + k];
  }
  int i2 = i - 14336;
  if (i2 >= 0 && i2 < 7168) {
    int e = i2 & 7, o = (i2 >> 3) & 31, g = i2 >> 8;
    int k = (g >> 2) * 32 + (g & 3) * 8 + e;
    W2p[i2] = (_Float16)W2[o * 224 + k];
  }
}

// ---------------- K3: conv1 — all 14 A-gathers issued before MFMAs (latency hiding)
__global__ __launch_bounds__(256, 4) void k_conv1(const _Float16* __restrict__ y,
    const int* __restrict__ neigh, const _Float16* __restrict__ W1p,
    _Float16* __restrict__ t1) {
  int b = blockIdx.y;
  int lane = threadIdx.x & 63, wv = threadIdx.x >> 6;
  int col = lane & 15, quad = lane >> 4;
  int v0 = blockIdx.x * 64 + wv * 16;
  int v = v0 + col;
  int vc = min(v, V2n - 1);
  const int* np = neigh + 7 * (size_t)vc;
  int idx[7];
#pragma unroll
  for (int j = 0; j < 7; ++j) idx[j] = np[j];
  const _Float16* yb = y + (size_t)b * V2n * 64 + quad * 8;
  h8 a[14];
#pragma unroll
  for (int j = 0; j < 7; ++j) {
    const _Float16* r = yb + (size_t)idx[j] * 64;
    a[2 * j]     = *(const h8*)r;          // c = quad*8 .. +7
    a[2 * j + 1] = *(const h8*)(r + 32);   // c = 32+quad*8 .. +7
  }
  f32x4 acc0 = {0.f, 0.f, 0.f, 0.f}, acc1 = {0.f, 0.f, 0.f, 0.f};
  const _Float16* wp = W1p + quad * 256;
#pragma unroll
  for (int kt = 0; kt < 14; ++kt) {
    h8 b0 = *(const h8*)(wp + (size_t)kt * 1024 + col * 8);
    h8 b1 = *(const h8*)(wp + (size_t)kt * 1024 + (16 + col) * 8);
    acc0 = __builtin_amdgcn_mfma_f32_16x16x32_f16(a[kt], b0, acc0, 0, 0, 0);
    acc1 = __builtin_amdgcn_mfma_f32_16x16x32_f16(a[kt], b1, acc1, 0, 0, 0);
  }
  // C/D: row(v) = quad*4+r, col(o) = lane&15 -> transpose via LDS for coalesced (v,o) stores
  __shared__ _Float16 tile[4][16][32];
#pragma unroll
  for (int r = 0; r < 4; ++r) {
    tile[wv][quad * 4 + r][col]      = (_Float16)acc0[r];
    tile[wv][quad * 4 + r][16 + col] = (_Float16)acc1[r];
  }
  __syncthreads();
  int row = threadIdx.x >> 2, ch = threadIdx.x & 3;
  int vv = blockIdx.x * 64 + row;
  if (vv < V2n) {
    h8 val = *(const h8*)&tile[row >> 4][row & 15][ch * 8];
    *(h8*)(t1 + ((size_t)b * V2n + vv) * 32 + ch * 8) = val;
  }
}

// ---------------- K4: per-(b,ch) sum/sumsq over fp16 t1
__global__ __launch_bounds__(256) void k_stats_h(const _Float16* __restrict__ t1,
                                                 float* __restrict__ sums) {
  int b = blockIdx.y, i = blockIdx.x;            // i in [0,32)
  int o = threadIdx.x & 31, w = threadIdx.x >> 5; // w in [0,8)
  const _Float16* tb = t1 + (size_t)b * V2n * 32;
  float s = 0.f, q = 0.f;
  for (int v = i * 8 + w; v < V2n; v += 256) {
    float x = h2f(tb[(size_t)v * 32 + o]);
    s += x; q += x * x;
  }
  __shared__ float ls[8][32], lq[8][32];
  ls[w][o] = s; lq[w][o] = q;
  __syncthreads();
  if (w == 0) {
#pragma unroll
    for (int k = 1; k < 8; ++k) { s += ls[k][o]; q += lq[k][o]; }
    atomicAdd(&sums[b * 32 + o], s);
    atomicAdd(&sums[128 + b * 32 + o], q);
  }
}

// ---------------- finalize: scale = g*rsqrt(var+eps), shift = be - mu*scale
__global__ void k_finalize(const float* __restrict__ sums, const float* __restrict__ g,
                           const float* __restrict__ be, float* __restrict__ sc,
                           float* __restrict__ sh) {
  int i = threadIdx.x;
  if (i >= 128) return;
  float inv = 1.0f / (float)V2n;
  float mu = sums[i] * inv;
  float var = fmaf(sums[128 + i], inv, -mu * mu);
  float rs = rsqrtf(var + 1e-5f);
  int o = i & 31;
  float scale = rs * g[o];
  sc[i] = scale;
  sh[i] = fmaf(-mu, scale, be[o]);
}

// ---------------- K5: conv2 — 7 gathers up-front, fused BN1+LeakyReLU; pre-BN2 -> d_out (B,32,V2)
__global__ __launch_bounds__(256, 4) void k_conv2(const _Float16* __restrict__ t1,
    const int* __restrict__ neigh, const _Float16* __restrict__ W2p,
    const float* __restrict__ sc1, const float* __restrict__ sh1,
    float* __restrict__ out) {
  int b = blockIdx.y;
  int lane = threadIdx.x & 63, wv = threadIdx.x >> 6;
  int col = lane & 15, quad = lane >> 4;
  int v0 = blockIdx.x * 64 + wv * 16;
  int v = v0 + col;
  int vc = min(v, V2n - 1);
  const int* np = neigh + 7 * (size_t)vc;
  int idx[7];
#pragma unroll
  for (int j = 0; j < 7; ++j) idx[j] = np[j];
  const _Float16* tb = t1 + (size_t)b * V2n * 32 + quad * 8;
  h8 raw[7];
#pragma unroll
  for (int j = 0; j < 7; ++j) raw[j] = *(const h8*)(tb + (size_t)idx[j] * 32);
  float sc[8], sh[8];
#pragma unroll
  for (int i = 0; i < 8; ++i) {
    sc[i] = sc1[b * 32 + quad * 8 + i];
    sh[i] = sh1[b * 32 + quad * 8 + i];
  }
  f32x4 acc0 = {0.f, 0.f, 0.f, 0.f}, acc1 = {0.f, 0.f, 0.f, 0.f};
  const _Float16* wp = W2p + quad * 256;
#pragma unroll
  for (int j = 0; j < 7; ++j) {
    h8 a;
#pragma unroll
    for (int e = 0; e < 8; ++e) {
      float f = fmaf(h2f(raw[j][e]), sc[e], sh[e]);
      f = fmaxf(f, 0.2f * f);             // LeakyReLU(0.2)
      a[e] = (_Float16)f;
    }
    h8 b0 = *(const h8*)(wp + (size_t)j * 1024 + col * 8);
    h8 b1 = *(const h8*)(wp + (size_t)j * 1024 + (16 + col) * 8);
    acc0 = __builtin_amdgcn_mfma_f32_16x16x32_f16(a, b0, acc0, 0, 0, 0);
    acc1 = __builtin_amdgcn_mfma_f32_16x16x32_f16(a, b1, acc1, 0, 0, 0);
  }
  float* ob = out + (size_t)b * 32 * V2n;
  int vrow = v0 + quad * 4;
  if (blockIdx.x != gridDim.x - 1) {
    float* p0 = ob + (size_t)col * V2n + vrow;          // V2 % 4 == 2 -> only 8B aligned
    *(float2*)p0       = make_float2(acc0[0], acc0[1]);
    *(float2*)(p0 + 2) = make_float2(acc0[2], acc0[3]);
    float* p1 = ob + (size_t)(16 + col) * V2n + vrow;
    *(float2*)p1       = make_float2(acc1[0], acc1[1]);
    *(float2*)(p1 + 2) = make_float2(acc1[2], acc1[3]);
  } else {
#pragma unroll
    for (int r = 0; r < 4; ++r) {
      if (vrow + r < V2n) {
        ob[(size_t)col * V2n + vrow + r]        = acc0[r];
        ob[(size_t)(16 + col) * V2n + vrow + r] = acc1[r];
      }
    }
  }
}

// ---------------- K6: per-(b,ch) stats over fp32 d_out rows
__global__ __launch_bounds__(256) void k_stats_f32(const float* __restrict__ out,
                                                   float* __restrict__ sums) {
  int row = blockIdx.y;       // b*32+o
  int qrt = blockIdx.x;       // 0..3
  const float* p = out + (size_t)row * V2n;
  int i0 = qrt * 20480;
  int iend = (qrt == 3) ? 81921 : i0 + 20480;   // float2 granularity, V2/2 = 81921
  float s = 0.f, q = 0.f;
  for (int i = i0 + (int)threadIdx.x; i < iend; i += 256) {
    float2 x = *(const float2*)(p + 2 * (size_t)i);
    s += x.x + x.y;
    q += x.x * x.x + x.y * x.y;
  }
  __shared__ float rs[256], rq[256];
  int t = threadIdx.x;
  rs[t] = s; rq[t] = q;
  __syncthreads();
  for (int k = 128; k > 0; k >>= 1) {
    if (t < k) { rs[t] += rs[t + k]; rq[t] += rq[t + k]; }
    __syncthreads();
  }
  if (t == 0) {
    atomicAdd(&sums[row], rs[0]);
    atomicAdd(&sums[128 + row], rq[0]);
  }
}

// ---------------- K7: in-place BN2 + LeakyReLU on d_out
__global__ __launch_bounds__(256) void k_bnorm(float* __restrict__ out,
    const float* __restrict__ sc, const float* __restrict__ sh) {
  int row = blockIdx.y, qrt = blockIdx.x;
  float scale = sc[row], shift = sh[row];
  float* p = out + (size_t)row * V2n;
  int i0 = qrt * 20480;
  int iend = (qrt == 3) ? 81921 : i0 + 20480;
  for (int i = i0 + (int)threadIdx.x; i < iend; i += 256) {
    float2 x = *(float2*)(p + 2 * (size_t)i);
    float a = fmaf(x.x, scale, shift); a = fmaxf(a, 0.2f * a);
    float b = fmaf(x.y, scale, shift); b = fmaxf(b, 0.2f * b);
    *(float2*)(p + 2 * (size_t)i) = make_float2(a, b);
  }
}

extern "C" void kernel_launch(void* const* d_in, const int* in_sizes, int n_in,
                              void* d_out, int out_size, void* d_ws, size_t ws_size,
                              hipStream_t stream) {
  const float* x1   = (const float*)d_in[0];
  const float* x2   = (const float*)d_in[1];
  const int*   neigh= (const int*)d_in[2];
  const int*   top  = (const int*)d_in[3];
  const int*   down = (const int*)d_in[4];
  const float* Wup  = (const float*)d_in[5];
  const float* bup  = (const float*)d_in[6];
  const float* W1   = (const float*)d_in[7];
  // d_in[8] = b1: constant per-channel shift, cancels exactly in BN -> skipped
  const float* g1   = (const float*)d_in[9];
  const float* be1  = (const float*)d_in[10];
  const float* W2   = (const float*)d_in[11];
  // d_in[12] = b2: cancels in BN -> skipped
  const float* g2   = (const float*)d_in[13];
  const float* be2  = (const float*)d_in[14];
  float* out = (float*)d_out;

  char* ws = (char*)d_ws;
  _Float16* rawq = (_Float16*)ws;                         //  73,403,904 B (dead after k_assemble)
  _Float16* y    = (_Float16*)(ws + 73403904);            //  83,887,104 B
  _Float16* t1   = (_Float16*)(ws + 157291008);           //  41,943,552 B
  float* stats   = (float*)(ws + 199234560);              //   4 KiB
  float* sums1 = stats;        float* sums2 = stats + 256;
  float* sc1   = stats + 512;  float* sh1   = stats + 640;
  float* sc2   = stats + 768;  float* sh2   = stats + 896;
  // W packs overlay the (dead-after-assemble) rawq region — zero extra ws.
  _Float16* W1p = rawq;                                    // 28,672 B
  _Float16* W2p = rawq + 14336;                            // 14,336 B

  hipMemsetAsync(sums1, 0, 512 * sizeof(float), stream);

  k_upconv   <<<dim3(641, Bn),  256, 0, stream>>>(x1, Wup, bup, rawq);
  k_assemble <<<dim3(641, Bn),  256, 0, stream>>>(x2, top, down, rawq, y);
  k_pack     <<<84, 256, 0, stream>>>(W1, W2, W1p, W2p);   // rawq dead from here
  k_conv1    <<<dim3(2561, Bn), 256, 0, stream>>>(y, neigh, W1p, t1);
  k_stats_h  <<<dim3(32, Bn),   256, 0, stream>>>(t1, sums1);
  k_finalize <<<1, 128, 0, stream>>>(sums1, g1, be1, sc1, sh1);
  k_conv2    <<<dim3(2561, Bn), 256, 0, stream>>>(t1, neigh, W2p, sc1, sh1, out);
  k_stats_f32<<<dim3(4, 128),   256, 0, stream>>>(out, sums2);
  k_finalize <<<1, 128, 0, stream>>>(sums2, g2, be2, sc2, sh2);
  k_bnorm    <<<dim3(4, 128),   256, 0, stream>>>(out, sc2, sh2);
}

// Round 3
// 705.890 us; speedup vs baseline: 1.6465x; 1.2426x over previous
//
#include <hip/hip_runtime.h>

#define V1n 40962
#define V2n 163842
#define Bn  4

typedef _Float16 h8   __attribute__((ext_vector_type(8)));
typedef float    f32x4 __attribute__((ext_vector_type(4)));

__device__ __forceinline__ float h2f(_Float16 h) { return (float)h; }

// ---------------- K0: pack Wup into fp16 MFMA B-fragment layout
// WupP[((kt*4+quad)*14 + nt)*128 + col*8 + e] = Wup[(nt*16+col)*64 + kt*32+quad*8+e]
__global__ __launch_bounds__(256) void k_pack_up(const float* __restrict__ Wup,
                                                 _Float16* __restrict__ WupP) {
  int i = blockIdx.x * 256 + threadIdx.x;
  if (i >= 14336) return;
  int e = i & 7, col = (i >> 3) & 15, g = i >> 7;   // g = (kt*4+quad)*14 + nt
  int nt = g % 14, kq = g / 14;
  int j = nt * 16 + col;
  int k = (kq >> 2) * 32 + (kq & 3) * 8 + e;
  WupP[i] = (_Float16)Wup[j * 64 + k];
}

// ---------------- K1: upconv GEMM via MFMA  raw[b][v][j] = sum_c x1[b][c][v]*Wup[j][c] + bup[j]
// wave = 16 vertices x 224 outputs, K=64 -> 28 MFMAs
__global__ __launch_bounds__(256, 4) void k_upconv(const float* __restrict__ x1,
    const float* __restrict__ bup, const _Float16* __restrict__ WupP,
    _Float16* __restrict__ rawq) {
  int b = blockIdx.y;
  int lane = threadIdx.x & 63, wv = threadIdx.x >> 6;
  int col = lane & 15, quad = lane >> 4;
  int v0 = blockIdx.x * 64 + wv * 16;
  int v = v0 + col;
  int vc = min(v, V1n - 1);
  const float* xb = x1 + (size_t)b * 64 * V1n + vc;
  // A fragments: lane holds A[m=col][k=quad*8+e] ; channels c = kt*32+quad*8+e
  float t0[8], t1v[8];
#pragma unroll
  for (int e = 0; e < 8; ++e) t0[e] = xb[(size_t)(quad * 8 + e) * V1n];
#pragma unroll
  for (int e = 0; e < 8; ++e) t1v[e] = xb[(size_t)(32 + quad * 8 + e) * V1n];
  h8 a0, a1;
#pragma unroll
  for (int e = 0; e < 8; ++e) { a0[e] = (_Float16)t0[e]; a1[e] = (_Float16)t1v[e]; }

  f32x4 acc[14];
#pragma unroll
  for (int nt = 0; nt < 14; ++nt) {
    float bv = bup[nt * 16 + col];
    acc[nt] = (f32x4){bv, bv, bv, bv};
  }
  const _Float16* wp0 = WupP + (size_t)(quad * 14) * 128 + col * 8;
  const _Float16* wp1 = WupP + (size_t)((4 + quad) * 14) * 128 + col * 8;
#pragma unroll
  for (int nt = 0; nt < 14; ++nt) {
    h8 b0 = *(const h8*)(wp0 + nt * 128);
    acc[nt] = __builtin_amdgcn_mfma_f32_16x16x32_f16(a0, b0, acc[nt], 0, 0, 0);
  }
#pragma unroll
  for (int nt = 0; nt < 14; ++nt) {
    h8 b1 = *(const h8*)(wp1 + nt * 128);
    acc[nt] = __builtin_amdgcn_mfma_f32_16x16x32_f16(a1, b1, acc[nt], 0, 0, 0);
  }
  // epilogue: per-wave LDS tile (16 v x 224 j) = exact linear image of rawq chunk
  __shared__ _Float16 tile[4][3584];
  _Float16* tw = tile[wv];
#pragma unroll
  for (int nt = 0; nt < 14; ++nt)
#pragma unroll
    for (int r = 0; r < 4; ++r)
      tw[(quad * 4 + r) * 224 + nt * 16 + col] = (_Float16)acc[nt][r];
  __syncthreads();
  _Float16* dst = rawq + ((size_t)b * V1n + v0) * 224;
  int rem = V1n - v0;
  if (rem >= 16) {
#pragma unroll
    for (int i = 0; i < 7; ++i)
      *(h8*)(dst + i * 512 + lane * 8) = *(const h8*)(tw + i * 512 + lane * 8);
  } else if (rem > 0) {
    for (int i = 0; i < 7; ++i) {
      int off = i * 512 + lane * 8;
      if (off / 224 < rem) *(h8*)(dst + off) = *(const h8*)(tw + off);
    }
  }
}

// ---------------- K2: assemble y[b][v][0:32]=upconv-scatter, [32:64]=x2^T   (fp16, row = MFMA feed)
__global__ __launch_bounds__(256) void k_assemble(const float* __restrict__ x2,
    const int* __restrict__ top, const int* __restrict__ down,
    const _Float16* __restrict__ rawq, _Float16* __restrict__ y) {
  int b = blockIdx.y;
  int v = blockIdx.x * 256 + threadIdx.x;
  if (v >= V2n) return;
  const _Float16* rb = rawq + (size_t)b * V1n * 224;
  h8 r0, r1, r2, r3;
  if (v < V1n) {
    int f = top[v];
    const _Float16* src = rb + (size_t)(f / 7) * 224 + (f % 7) * 32;
    r0 = *(const h8*)src;        r1 = *(const h8*)(src + 8);
    r2 = *(const h8*)(src + 16); r3 = *(const h8*)(src + 24);
  } else {
    int k = v - V1n;
    int d0 = down[2 * k], d1 = down[2 * k + 1];
    const _Float16* se = rb + (size_t)(d0 / 7) * 224 + (d0 % 7) * 32;
    const _Float16* so = rb + (size_t)(d1 / 7) * 224 + (d1 % 7) * 32;
    h8 a0 = *(const h8*)se,        a1 = *(const h8*)(se + 8);
    h8 a2 = *(const h8*)(se + 16), a3 = *(const h8*)(se + 24);
    h8 c0 = *(const h8*)so,        c1 = *(const h8*)(so + 8);
    h8 c2 = *(const h8*)(so + 16), c3 = *(const h8*)(so + 24);
#pragma unroll
    for (int i = 0; i < 4; ++i) {
      // torch view semantics: out ch o<16 pairs (2o,2o+1) of even row; o>=16 of odd row
      r0[i]     = (_Float16)(0.5f * (h2f(a0[2 * i]) + h2f(a0[2 * i + 1])));
      r0[4 + i] = (_Float16)(0.5f * (h2f(a1[2 * i]) + h2f(a1[2 * i + 1])));
      r1[i]     = (_Float16)(0.5f * (h2f(a2[2 * i]) + h2f(a2[2 * i + 1])));
      r1[4 + i] = (_Float16)(0.5f * (h2f(a3[2 * i]) + h2f(a3[2 * i + 1])));
      r2[i]     = (_Float16)(0.5f * (h2f(c0[2 * i]) + h2f(c0[2 * i + 1])));
      r2[4 + i] = (_Float16)(0.5f * (h2f(c1[2 * i]) + h2f(c1[2 * i + 1])));
      r3[i]     = (_Float16)(0.5f * (h2f(c2[2 * i]) + h2f(c2[2 * i + 1])));
      r3[4 + i] = (_Float16)(0.5f * (h2f(c3[2 * i]) + h2f(c3[2 * i + 1])));
    }
  }
  _Float16* dst = y + ((size_t)b * V2n + v) * 64;
  *(h8*)(dst)      = r0; *(h8*)(dst + 8)  = r1;
  *(h8*)(dst + 16) = r2; *(h8*)(dst + 24) = r3;
  const float* xp = x2 + (size_t)b * 32 * V2n + v;
#pragma unroll
  for (int g2 = 0; g2 < 4; ++g2) {
    h8 px;
#pragma unroll
    for (int e = 0; e < 8; ++e) px[e] = (_Float16)xp[(size_t)(g2 * 8 + e) * V2n];
    *(h8*)(dst + 32 + g2 * 8) = px;
  }
}

// ---------------- K2b: pack W1/W2 into fp16 MFMA B-fragment layout
__global__ __launch_bounds__(256) void k_pack(const float* __restrict__ W1,
    const float* __restrict__ W2, _Float16* __restrict__ W1p,
    _Float16* __restrict__ W2p) {
  int i = blockIdx.x * 256 + threadIdx.x;
  if (i < 14336) {
    int e = i & 7, o = (i >> 3) & 31, g = i >> 8;       // g = kt*4+quad
    int k = (g >> 2) * 32 + (g & 3) * 8 + e;
    W1p[i] = (_Float16)W1[o * 448 + k];
  }
  int i2 = i - 14336;
  if (i2 >= 0 && i2 < 7168) {
    int e = i2 & 7, o = (i2 >> 3) & 31, g = i2 >> 8;
    int k = (g >> 2) * 32 + (g & 3) * 8 + e;
    W2p[i2] = (_Float16)W2[o * 224 + k];
  }
}

// ---------------- K3: conv1 — all 14 A-gathers issued before MFMAs (latency hiding)
__global__ __launch_bounds__(256, 4) void k_conv1(const _Float16* __restrict__ y,
    const int* __restrict__ neigh, const _Float16* __restrict__ W1p,
    _Float16* __restrict__ t1) {
  int b = blockIdx.y;
  int lane = threadIdx.x & 63, wv = threadIdx.x >> 6;
  int col = lane & 15, quad = lane >> 4;
  int v0 = blockIdx.x * 64 + wv * 16;
  int v = v0 + col;
  int vc = min(v, V2n - 1);
  const int* np = neigh + 7 * (size_t)vc;
  int idx[7];
#pragma unroll
  for (int j = 0; j < 7; ++j) idx[j] = np[j];
  const _Float16* yb = y + (size_t)b * V2n * 64 + quad * 8;
  h8 a[14];
#pragma unroll
  for (int j = 0; j < 7; ++j) {
    const _Float16* r = yb + (size_t)idx[j] * 64;
    a[2 * j]     = *(const h8*)r;          // c = quad*8 .. +7
    a[2 * j + 1] = *(const h8*)(r + 32);   // c = 32+quad*8 .. +7
  }
  f32x4 acc0 = {0.f, 0.f, 0.f, 0.f}, acc1 = {0.f, 0.f, 0.f, 0.f};
  const _Float16* wp = W1p + quad * 256;
#pragma unroll
  for (int kt = 0; kt < 14; ++kt) {
    h8 b0 = *(const h8*)(wp + (size_t)kt * 1024 + col * 8);
    h8 b1 = *(const h8*)(wp + (size_t)kt * 1024 + (16 + col) * 8);
    acc0 = __builtin_amdgcn_mfma_f32_16x16x32_f16(a[kt], b0, acc0, 0, 0, 0);
    acc1 = __builtin_amdgcn_mfma_f32_16x16x32_f16(a[kt], b1, acc1, 0, 0, 0);
  }
  __shared__ _Float16 tile[4][16][32];
#pragma unroll
  for (int r = 0; r < 4; ++r) {
    tile[wv][quad * 4 + r][col]      = (_Float16)acc0[r];
    tile[wv][quad * 4 + r][16 + col] = (_Float16)acc1[r];
  }
  __syncthreads();
  int row = threadIdx.x >> 2, ch = threadIdx.x & 3;
  int vv = blockIdx.x * 64 + row;
  if (vv < V2n) {
    h8 val = *(const h8*)&tile[row >> 4][row & 15][ch * 8];
    *(h8*)(t1 + ((size_t)b * V2n + vv) * 32 + ch * 8) = val;
  }
}

// ---------------- K4: per-(b,ch) sum/sumsq over fp16 t1
__global__ __launch_bounds__(256) void k_stats_h(const _Float16* __restrict__ t1,
                                                 float* __restrict__ sums) {
  int b = blockIdx.y, i = blockIdx.x;            // i in [0,32)
  int o = threadIdx.x & 31, w = threadIdx.x >> 5; // w in [0,8)
  const _Float16* tb = t1 + (size_t)b * V2n * 32;
  float s = 0.f, q = 0.f;
  for (int v = i * 8 + w; v < V2n; v += 256) {
    float x = h2f(tb[(size_t)v * 32 + o]);
    s += x; q += x * x;
  }
  __shared__ float ls[8][32], lq[8][32];
  ls[w][o] = s; lq[w][o] = q;
  __syncthreads();
  if (w == 0) {
#pragma unroll
    for (int k = 1; k < 8; ++k) { s += ls[k][o]; q += lq[k][o]; }
    atomicAdd(&sums[b * 32 + o], s);
    atomicAdd(&sums[128 + b * 32 + o], q);
  }
}

// ---------------- finalize: scale = g*rsqrt(var+eps), shift = be - mu*scale
__global__ void k_finalize(const float* __restrict__ sums, const float* __restrict__ g,
                           const float* __restrict__ be, float* __restrict__ sc,
                           float* __restrict__ sh) {
  int i = threadIdx.x;
  if (i >= 128) return;
  float inv = 1.0f / (float)V2n;
  float mu = sums[i] * inv;
  float var = fmaf(sums[128 + i], inv, -mu * mu);
  float rs = rsqrtf(var + 1e-5f);
  int o = i & 31;
  float scale = rs * g[o];
  sc[i] = scale;
  sh[i] = fmaf(-mu, scale, be[o]);
}

// ---------------- K5: conv2 — 7 gathers up-front, fused BN1+LeakyReLU; pre-BN2 -> d_out (B,32,V2)
__global__ __launch_bounds__(256, 4) void k_conv2(const _Float16* __restrict__ t1,
    const int* __restrict__ neigh, const _Float16* __restrict__ W2p,
    const float* __restrict__ sc1, const float* __restrict__ sh1,
    float* __restrict__ out) {
  int b = blockIdx.y;
  int lane = threadIdx.x & 63, wv = threadIdx.x >> 6;
  int col = lane & 15, quad = lane >> 4;
  int v0 = blockIdx.x * 64 + wv * 16;
  int v = v0 + col;
  int vc = min(v, V2n - 1);
  const int* np = neigh + 7 * (size_t)vc;
  int idx[7];
#pragma unroll
  for (int j = 0; j < 7; ++j) idx[j] = np[j];
  const _Float16* tb = t1 + (size_t)b * V2n * 32 + quad * 8;
  h8 raw[7];
#pragma unroll
  for (int j = 0; j < 7; ++j) raw[j] = *(const h8*)(tb + (size_t)idx[j] * 32);
  float sc[8], sh[8];
#pragma unroll
  for (int i = 0; i < 8; ++i) {
    sc[i] = sc1[b * 32 + quad * 8 + i];
    sh[i] = sh1[b * 32 + quad * 8 + i];
  }
  f32x4 acc0 = {0.f, 0.f, 0.f, 0.f}, acc1 = {0.f, 0.f, 0.f, 0.f};
  const _Float16* wp = W2p + quad * 256;
#pragma unroll
  for (int j = 0; j < 7; ++j) {
    h8 a;
#pragma unroll
    for (int e = 0; e < 8; ++e) {
      float f = fmaf(h2f(raw[j][e]), sc[e], sh[e]);
      f = fmaxf(f, 0.2f * f);             // LeakyReLU(0.2)
      a[e] = (_Float16)f;
    }
    h8 b0 = *(const h8*)(wp + (size_t)j * 1024 + col * 8);
    h8 b1 = *(const h8*)(wp + (size_t)j * 1024 + (16 + col) * 8);
    acc0 = __builtin_amdgcn_mfma_f32_16x16x32_f16(a, b0, acc0, 0, 0, 0);
    acc1 = __builtin_amdgcn_mfma_f32_16x16x32_f16(a, b1, acc1, 0, 0, 0);
  }
  float* ob = out + (size_t)b * 32 * V2n;
  int vrow = v0 + quad * 4;
  if (blockIdx.x != gridDim.x - 1) {
    float* p0 = ob + (size_t)col * V2n + vrow;          // V2 % 4 == 2 -> only 8B aligned
    *(float2*)p0       = make_float2(acc0[0], acc0[1]);
    *(float2*)(p0 + 2) = make_float2(acc0[2], acc0[3]);
    float* p1 = ob + (size_t)(16 + col) * V2n + vrow;
    *(float2*)p1       = make_float2(acc1[0], acc1[1]);
    *(float2*)(p1 + 2) = make_float2(acc1[2], acc1[3]);
  } else {
#pragma unroll
    for (int r = 0; r < 4; ++r) {
      if (vrow + r < V2n) {
        ob[(size_t)col * V2n + vrow + r]        = acc0[r];
        ob[(size_t)(16 + col) * V2n + vrow + r] = acc1[r];
      }
    }
  }
}

// ---------------- K6: per-(b,ch) stats over fp32 d_out rows
__global__ __launch_bounds__(256) void k_stats_f32(const float* __restrict__ out,
                                                   float* __restrict__ sums) {
  int row = blockIdx.y;       // b*32+o
  int qrt = blockIdx.x;       // 0..3
  const float* p = out + (size_t)row * V2n;
  int i0 = qrt * 20480;
  int iend = (qrt == 3) ? 81921 : i0 + 20480;   // float2 granularity, V2/2 = 81921
  float s = 0.f, q = 0.f;
  for (int i = i0 + (int)threadIdx.x; i < iend; i += 256) {
    float2 x = *(const float2*)(p + 2 * (size_t)i);
    s += x.x + x.y;
    q += x.x * x.x + x.y * x.y;
  }
  __shared__ float rs[256], rq[256];
  int t = threadIdx.x;
  rs[t] = s; rq[t] = q;
  __syncthreads();
  for (int k = 128; k > 0; k >>= 1) {
    if (t < k) { rs[t] += rs[t + k]; rq[t] += rq[t + k]; }
    __syncthreads();
  }
  if (t == 0) {
    atomicAdd(&sums[row], rs[0]);
    atomicAdd(&sums[128 + row], rq[0]);
  }
}

// ---------------- K7: in-place BN2 + LeakyReLU on d_out
__global__ __launch_bounds__(256) void k_bnorm(float* __restrict__ out,
    const float* __restrict__ sc, const float* __restrict__ sh) {
  int row = blockIdx.y, qrt = blockIdx.x;
  float scale = sc[row], shift = sh[row];
  float* p = out + (size_t)row * V2n;
  int i0 = qrt * 20480;
  int iend = (qrt == 3) ? 81921 : i0 + 20480;
  for (int i = i0 + (int)threadIdx.x; i < iend; i += 256) {
    float2 x = *(float2*)(p + 2 * (size_t)i);
    float a = fmaf(x.x, scale, shift); a = fmaxf(a, 0.2f * a);
    float b = fmaf(x.y, scale, shift); b = fmaxf(b, 0.2f * b);
    *(float2*)(p + 2 * (size_t)i) = make_float2(a, b);
  }
}

extern "C" void kernel_launch(void* const* d_in, const int* in_sizes, int n_in,
                              void* d_out, int out_size, void* d_ws, size_t ws_size,
                              hipStream_t stream) {
  const float* x1   = (const float*)d_in[0];
  const float* x2   = (const float*)d_in[1];
  const int*   neigh= (const int*)d_in[2];
  const int*   top  = (const int*)d_in[3];
  const int*   down = (const int*)d_in[4];
  const float* Wup  = (const float*)d_in[5];
  const float* bup  = (const float*)d_in[6];
  const float* W1   = (const float*)d_in[7];
  // d_in[8] = b1: cancels exactly in BN -> skipped
  const float* g1   = (const float*)d_in[9];
  const float* be1  = (const float*)d_in[10];
  const float* W2   = (const float*)d_in[11];
  // d_in[12] = b2: cancels in BN -> skipped
  const float* g2   = (const float*)d_in[13];
  const float* be2  = (const float*)d_in[14];
  float* out = (float*)d_out;

  char* ws = (char*)d_ws;
  _Float16* rawq = (_Float16*)ws;                         //  73,403,904 B (dead after k_assemble)
  _Float16* y    = (_Float16*)(ws + 73403904);            //  83,887,104 B
  _Float16* t1   = (_Float16*)(ws + 157291008);           //  41,943,552 B
  float* stats   = (float*)(ws + 199234560);              //   4 KiB
  float* sums1 = stats;        float* sums2 = stats + 256;
  float* sc1   = stats + 512;  float* sh1   = stats + 640;
  float* sc2   = stats + 768;  float* sh2   = stats + 896;
  // WupP lives at t1 base: used only by k_upconv, t1 written later by k_conv1.
  _Float16* WupP = t1;                                     // 28,672 B
  // W1p/W2p overlay the (dead-after-assemble) rawq region.
  _Float16* W1p = rawq;                                    // 28,672 B
  _Float16* W2p = rawq + 14336;                            // 14,336 B

  hipMemsetAsync(sums1, 0, 512 * sizeof(float), stream);

  k_pack_up  <<<56, 256, 0, stream>>>(Wup, WupP);
  k_upconv   <<<dim3(641, Bn),  256, 0, stream>>>(x1, bup, WupP, rawq);
  k_assemble <<<dim3(641, Bn),  256, 0, stream>>>(x2, top, down, rawq, y);
  k_pack     <<<84, 256, 0, stream>>>(W1, W2, W1p, W2p);   // rawq dead from here
  k_conv1    <<<dim3(2561, Bn), 256, 0, stream>>>(y, neigh, W1p, t1);
  k_stats_h  <<<dim3(32, Bn),   256, 0, stream>>>(t1, sums1);
  k_finalize <<<1, 128, 0, stream>>>(sums1, g1, be1, sc1, sh1);
  k_conv2    <<<dim3(2561, Bn), 256, 0, stream>>>(t1, neigh, W2p, sc1, sh1, out);
  k_stats_f32<<<dim3(4, 128),   256, 0, stream>>>(out, sums2);
  k_finalize <<<1, 128, 0, stream>>>(sums2, g2, be2, sc2, sh2);
  k_bnorm    <<<dim3(4, 128),   256, 0, stream>>>(out, sc2, sh2);
}

// Round 4
// 504.698 us; speedup vs baseline: 2.3028x; 1.3986x over previous
//
#include <hip/hip_runtime.h>

#define V1n 40962
#define V2n 163842
#define Bn  4

typedef _Float16 h8   __attribute__((ext_vector_type(8)));
typedef float    f32x4 __attribute__((ext_vector_type(4)));

__device__ __forceinline__ float h2f(_Float16 h) { return (float)h; }

// ---------------- K0: pack Wup into fp16 MFMA B-fragment layout
__global__ __launch_bounds__(256) void k_pack_up(const float* __restrict__ Wup,
                                                 _Float16* __restrict__ WupP) {
  int i = blockIdx.x * 256 + threadIdx.x;
  if (i >= 14336) return;
  int e = i & 7, col = (i >> 3) & 15, g = i >> 7;   // g = (kt*4+quad)*14 + nt
  int nt = g % 14, kq = g / 14;
  int j = nt * 16 + col;
  int k = (kq >> 2) * 32 + (kq & 3) * 8 + e;
  WupP[i] = (_Float16)Wup[j * 64 + k];
}

// ---------------- K1: upconv GEMM via MFMA (16 vertices x 224 outputs per wave, K=64)
__global__ __launch_bounds__(256, 4) void k_upconv(const float* __restrict__ x1,
    const float* __restrict__ bup, const _Float16* __restrict__ WupP,
    _Float16* __restrict__ rawq) {
  int b = blockIdx.y;
  int lane = threadIdx.x & 63, wv = threadIdx.x >> 6;
  int col = lane & 15, quad = lane >> 4;
  int v0 = blockIdx.x * 64 + wv * 16;
  int v = v0 + col;
  int vc = min(v, V1n - 1);
  const float* xb = x1 + (size_t)b * 64 * V1n + vc;
  float t0[8], t1v[8];
#pragma unroll
  for (int e = 0; e < 8; ++e) t0[e] = xb[(size_t)(quad * 8 + e) * V1n];
#pragma unroll
  for (int e = 0; e < 8; ++e) t1v[e] = xb[(size_t)(32 + quad * 8 + e) * V1n];
  h8 a0, a1;
#pragma unroll
  for (int e = 0; e < 8; ++e) { a0[e] = (_Float16)t0[e]; a1[e] = (_Float16)t1v[e]; }

  f32x4 acc[14];
#pragma unroll
  for (int nt = 0; nt < 14; ++nt) {
    float bv = bup[nt * 16 + col];
    acc[nt] = (f32x4){bv, bv, bv, bv};
  }
  const _Float16* wp0 = WupP + (size_t)(quad * 14) * 128 + col * 8;
  const _Float16* wp1 = WupP + (size_t)((4 + quad) * 14) * 128 + col * 8;
#pragma unroll
  for (int nt = 0; nt < 14; ++nt) {
    h8 b0 = *(const h8*)(wp0 + nt * 128);
    acc[nt] = __builtin_amdgcn_mfma_f32_16x16x32_f16(a0, b0, acc[nt], 0, 0, 0);
  }
#pragma unroll
  for (int nt = 0; nt < 14; ++nt) {
    h8 b1 = *(const h8*)(wp1 + nt * 128);
    acc[nt] = __builtin_amdgcn_mfma_f32_16x16x32_f16(a1, b1, acc[nt], 0, 0, 0);
  }
  __shared__ _Float16 tile[4][3584];
  _Float16* tw = tile[wv];
#pragma unroll
  for (int nt = 0; nt < 14; ++nt)
#pragma unroll
    for (int r = 0; r < 4; ++r)
      tw[(quad * 4 + r) * 224 + nt * 16 + col] = (_Float16)acc[nt][r];
  __syncthreads();
  _Float16* dst = rawq + ((size_t)b * V1n + v0) * 224;
  int rem = V1n - v0;
  if (rem >= 16) {
#pragma unroll
    for (int i = 0; i < 7; ++i)
      *(h8*)(dst + i * 512 + lane * 8) = *(const h8*)(tw + i * 512 + lane * 8);
  } else if (rem > 0) {
    for (int i = 0; i < 7; ++i) {
      int off = i * 512 + lane * 8;
      if (off / 224 < rem) *(h8*)(dst + off) = *(const h8*)(tw + off);
    }
  }
}

// ---------------- K2: assemble y[b][v][0:32]=upconv-scatter, [32:64]=x2^T   (fp16, row = MFMA feed)
__global__ __launch_bounds__(256) void k_assemble(const float* __restrict__ x2,
    const int* __restrict__ top, const int* __restrict__ down,
    const _Float16* __restrict__ rawq, _Float16* __restrict__ y) {
  int b = blockIdx.y;
  int v = blockIdx.x * 256 + threadIdx.x;
  if (v >= V2n) return;
  const _Float16* rb = rawq + (size_t)b * V1n * 224;
  h8 r0, r1, r2, r3;
  if (v < V1n) {
    int f = top[v];
    const _Float16* src = rb + (size_t)(f / 7) * 224 + (f % 7) * 32;
    r0 = *(const h8*)src;        r1 = *(const h8*)(src + 8);
    r2 = *(const h8*)(src + 16); r3 = *(const h8*)(src + 24);
  } else {
    int k = v - V1n;
    int d0 = down[2 * k], d1 = down[2 * k + 1];
    const _Float16* se = rb + (size_t)(d0 / 7) * 224 + (d0 % 7) * 32;
    const _Float16* so = rb + (size_t)(d1 / 7) * 224 + (d1 % 7) * 32;
    h8 a0 = *(const h8*)se,        a1 = *(const h8*)(se + 8);
    h8 a2 = *(const h8*)(se + 16), a3 = *(const h8*)(se + 24);
    h8 c0 = *(const h8*)so,        c1 = *(const h8*)(so + 8);
    h8 c2 = *(const h8*)(so + 16), c3 = *(const h8*)(so + 24);
#pragma unroll
    for (int i = 0; i < 4; ++i) {
      r0[i]     = (_Float16)(0.5f * (h2f(a0[2 * i]) + h2f(a0[2 * i + 1])));
      r0[4 + i] = (_Float16)(0.5f * (h2f(a1[2 * i]) + h2f(a1[2 * i + 1])));
      r1[i]     = (_Float16)(0.5f * (h2f(a2[2 * i]) + h2f(a2[2 * i + 1])));
      r1[4 + i] = (_Float16)(0.5f * (h2f(a3[2 * i]) + h2f(a3[2 * i + 1])));
      r2[i]     = (_Float16)(0.5f * (h2f(c0[2 * i]) + h2f(c0[2 * i + 1])));
      r2[4 + i] = (_Float16)(0.5f * (h2f(c1[2 * i]) + h2f(c1[2 * i + 1])));
      r3[i]     = (_Float16)(0.5f * (h2f(c2[2 * i]) + h2f(c2[2 * i + 1])));
      r3[4 + i] = (_Float16)(0.5f * (h2f(c3[2 * i]) + h2f(c3[2 * i + 1])));
    }
  }
  _Float16* dst = y + ((size_t)b * V2n + v) * 64;
  *(h8*)(dst)      = r0; *(h8*)(dst + 8)  = r1;
  *(h8*)(dst + 16) = r2; *(h8*)(dst + 24) = r3;
  const float* xp = x2 + (size_t)b * 32 * V2n + v;
#pragma unroll
  for (int g2 = 0; g2 < 4; ++g2) {
    h8 px;
#pragma unroll
    for (int e = 0; e < 8; ++e) px[e] = (_Float16)xp[(size_t)(g2 * 8 + e) * V2n];
    *(h8*)(dst + 32 + g2 * 8) = px;
  }
}

// ---------------- K2b: pack W1/W2 into fp16 MFMA B-fragment layout
__global__ __launch_bounds__(256) void k_pack(const float* __restrict__ W1,
    const float* __restrict__ W2, _Float16* __restrict__ W1p,
    _Float16* __restrict__ W2p) {
  int i = blockIdx.x * 256 + threadIdx.x;
  if (i < 14336) {
    int e = i & 7, o = (i >> 3) & 31, g = i >> 8;       // g = kt*4+quad
    int k = (g >> 2) * 32 + (g & 3) * 8 + e;
    W1p[i] = (_Float16)W1[o * 448 + k];
  }
  int i2 = i - 14336;
  if (i2 >= 0 && i2 < 7168) {
    int e = i2 & 7, o = (i2 >> 3) & 31, g = i2 >> 8;
    int k = (g >> 2) * 32 + (g & 3) * 8 + e;
    W2p[i2] = (_Float16)W2[o * 224 + k];
  }
}

// ---------------- K3: conv1 + fused BN1-stats (per-channel sum/sumsq, 64-way replicated atomics)
__global__ __launch_bounds__(256, 4) void k_conv1(const _Float16* __restrict__ y,
    const int* __restrict__ neigh, const _Float16* __restrict__ W1p,
    _Float16* __restrict__ t1, float* __restrict__ sumsR) {
  int b = blockIdx.y;
  int lane = threadIdx.x & 63, wv = threadIdx.x >> 6;
  int col = lane & 15, quad = lane >> 4;
  int v0 = blockIdx.x * 64 + wv * 16;
  int v = v0 + col;
  int vc = min(v, V2n - 1);
  const int* np = neigh + 7 * (size_t)vc;
  int idx[7];
#pragma unroll
  for (int j = 0; j < 7; ++j) idx[j] = np[j];
  const _Float16* yb = y + (size_t)b * V2n * 64 + quad * 8;
  h8 a[14];
#pragma unroll
  for (int j = 0; j < 7; ++j) {
    const _Float16* r = yb + (size_t)idx[j] * 64;
    a[2 * j]     = *(const h8*)r;
    a[2 * j + 1] = *(const h8*)(r + 32);
  }
  f32x4 acc0 = {0.f, 0.f, 0.f, 0.f}, acc1 = {0.f, 0.f, 0.f, 0.f};
  const _Float16* wp = W1p + quad * 256;
#pragma unroll
  for (int kt = 0; kt < 14; ++kt) {
    h8 b0 = *(const h8*)(wp + (size_t)kt * 1024 + col * 8);
    h8 b1 = *(const h8*)(wp + (size_t)kt * 1024 + (16 + col) * 8);
    acc0 = __builtin_amdgcn_mfma_f32_16x16x32_f16(a[kt], b0, acc0, 0, 0, 0);
    acc1 = __builtin_amdgcn_mfma_f32_16x16x32_f16(a[kt], b1, acc1, 0, 0, 0);
  }
  __shared__ _Float16 tile[4][16][32];
  __shared__ float red[4][4][16];
#pragma unroll
  for (int r = 0; r < 4; ++r) {
    tile[wv][quad * 4 + r][col]      = (_Float16)acc0[r];
    tile[wv][quad * 4 + r][16 + col] = (_Float16)acc1[r];
  }
  __syncthreads();
  int row = threadIdx.x >> 2, ch = threadIdx.x & 3;
  int vv = blockIdx.x * 64 + row;
  float s[8], q[8];
#pragma unroll
  for (int e = 0; e < 8; ++e) { s[e] = 0.f; q[e] = 0.f; }
  if (vv < V2n) {
    h8 val = *(const h8*)&tile[row >> 4][row & 15][ch * 8];
    *(h8*)(t1 + ((size_t)b * V2n + vv) * 32 + ch * 8) = val;
#pragma unroll
    for (int e = 0; e < 8; ++e) { float x = h2f(val[e]); s[e] = x; q[e] = x * x; }
  }
  // butterfly over the 16 same-ch lanes of this wave (lane & 3 == ch)
#pragma unroll
  for (int m = 4; m <= 32; m <<= 1) {
#pragma unroll
    for (int e = 0; e < 8; ++e) { s[e] += __shfl_xor(s[e], m); q[e] += __shfl_xor(q[e], m); }
  }
  if (lane < 4) {
#pragma unroll
    for (int e = 0; e < 8; ++e) { red[wv][lane][e] = s[e]; red[wv][lane][8 + e] = q[e]; }
  }
  __syncthreads();
  if (threadIdx.x < 64) {
    int chh = threadIdx.x >> 4, e = threadIdx.x & 15;
    float v4 = red[0][chh][e] + red[1][chh][e] + red[2][chh][e] + red[3][chh][e];
    int c = chh * 8 + (e & 7);
    int rep = blockIdx.x & 63;
    float* dst = sumsR + rep * 256 + ((e < 8) ? (b * 32 + c) : (128 + b * 32 + c));
    atomicAdd(dst, v4);
  }
}

// ---------------- finalize: fold 64 replicas; scale = g*rsqrt(var+eps), shift = be - mu*scale
__global__ void k_finalize(const float* __restrict__ sumsR, const float* __restrict__ g,
                           const float* __restrict__ be, float* __restrict__ sc,
                           float* __restrict__ sh) {
  int i = threadIdx.x;
  if (i >= 128) return;
  float s = 0.f, q = 0.f;
  for (int r = 0; r < 64; ++r) { s += sumsR[r * 256 + i]; q += sumsR[r * 256 + 128 + i]; }
  float inv = 1.0f / (float)V2n;
  float mu = s * inv;
  float var = fmaf(q, inv, -mu * mu);
  float rs = rsqrtf(var + 1e-5f);
  int o = i & 31;
  float scale = rs * g[o];
  sc[i] = scale;
  sh[i] = fmaf(-mu, scale, be[o]);
}

// ---------------- K5: conv2 + fused BN1/LReLU on A + fused BN2-stats; pre-BN2 -> d_out (B,32,V2)
__global__ __launch_bounds__(256, 4) void k_conv2(const _Float16* __restrict__ t1,
    const int* __restrict__ neigh, const _Float16* __restrict__ W2p,
    const float* __restrict__ sc1, const float* __restrict__ sh1,
    float* __restrict__ out, float* __restrict__ sumsR) {
  int b = blockIdx.y;
  int lane = threadIdx.x & 63, wv = threadIdx.x >> 6;
  int col = lane & 15, quad = lane >> 4;
  int v0 = blockIdx.x * 64 + wv * 16;
  int v = v0 + col;
  int vc = min(v, V2n - 1);
  const int* np = neigh + 7 * (size_t)vc;
  int idx[7];
#pragma unroll
  for (int j = 0; j < 7; ++j) idx[j] = np[j];
  const _Float16* tb = t1 + (size_t)b * V2n * 32 + quad * 8;
  h8 raw[7];
#pragma unroll
  for (int j = 0; j < 7; ++j) raw[j] = *(const h8*)(tb + (size_t)idx[j] * 32);
  float sc[8], sh[8];
#pragma unroll
  for (int i = 0; i < 8; ++i) {
    sc[i] = sc1[b * 32 + quad * 8 + i];
    sh[i] = sh1[b * 32 + quad * 8 + i];
  }
  f32x4 acc0 = {0.f, 0.f, 0.f, 0.f}, acc1 = {0.f, 0.f, 0.f, 0.f};
  const _Float16* wp = W2p + quad * 256;
#pragma unroll
  for (int j = 0; j < 7; ++j) {
    h8 a;
#pragma unroll
    for (int e = 0; e < 8; ++e) {
      float f = fmaf(h2f(raw[j][e]), sc[e], sh[e]);
      f = fmaxf(f, 0.2f * f);
      a[e] = (_Float16)f;
    }
    h8 b0 = *(const h8*)(wp + (size_t)j * 1024 + col * 8);
    h8 b1 = *(const h8*)(wp + (size_t)j * 1024 + (16 + col) * 8);
    acc0 = __builtin_amdgcn_mfma_f32_16x16x32_f16(a, b0, acc0, 0, 0, 0);
    acc1 = __builtin_amdgcn_mfma_f32_16x16x32_f16(a, b1, acc1, 0, 0, 0);
  }
  float* ob = out + (size_t)b * 32 * V2n;
  int vrow = v0 + quad * 4;
  float s0 = 0.f, q0 = 0.f, s1 = 0.f, q1 = 0.f;
  if (blockIdx.x != gridDim.x - 1) {
    float* p0 = ob + (size_t)col * V2n + vrow;
    *(float2*)p0       = make_float2(acc0[0], acc0[1]);
    *(float2*)(p0 + 2) = make_float2(acc0[2], acc0[3]);
    float* p1 = ob + (size_t)(16 + col) * V2n + vrow;
    *(float2*)p1       = make_float2(acc1[0], acc1[1]);
    *(float2*)(p1 + 2) = make_float2(acc1[2], acc1[3]);
#pragma unroll
    for (int r = 0; r < 4; ++r) {
      s0 += acc0[r]; q0 += acc0[r] * acc0[r];
      s1 += acc1[r]; q1 += acc1[r] * acc1[r];
    }
  } else {
#pragma unroll
    for (int r = 0; r < 4; ++r) {
      if (vrow + r < V2n) {
        ob[(size_t)col * V2n + vrow + r]        = acc0[r];
        ob[(size_t)(16 + col) * V2n + vrow + r] = acc1[r];
        s0 += acc0[r]; q0 += acc0[r] * acc0[r];
        s1 += acc1[r]; q1 += acc1[r] * acc1[r];
      }
    }
  }
  // butterfly over the 4 same-col lanes (quads) of this wave
#pragma unroll
  for (int m = 16; m <= 32; m <<= 1) {
    s0 += __shfl_xor(s0, m); q0 += __shfl_xor(q0, m);
    s1 += __shfl_xor(s1, m); q1 += __shfl_xor(q1, m);
  }
  __shared__ float red2[4][16][4];
  if (lane < 16) {
    red2[wv][col][0] = s0; red2[wv][col][1] = q0;
    red2[wv][col][2] = s1; red2[wv][col][3] = q1;
  }
  __syncthreads();
  if (threadIdx.x < 64) {
    int cc = threadIdx.x & 15, which = threadIdx.x >> 4;
    float v4 = red2[0][cc][which] + red2[1][cc][which] +
               red2[2][cc][which] + red2[3][cc][which];
    int c = (which & 2) ? cc + 16 : cc;
    int rep = blockIdx.x & 63;
    float* dst = sumsR + rep * 256 + ((which & 1) ? (128 + b * 32 + c) : (b * 32 + c));
    atomicAdd(dst, v4);
  }
}

// ---------------- K7: in-place BN2 + LeakyReLU on d_out
__global__ __launch_bounds__(256) void k_bnorm(float* __restrict__ out,
    const float* __restrict__ sc, const float* __restrict__ sh) {
  int row = blockIdx.y, qrt = blockIdx.x;
  float scale = sc[row], shift = sh[row];
  float* p = out + (size_t)row * V2n;
  int i0 = qrt * 20480;
  int iend = (qrt == 3) ? 81921 : i0 + 20480;
  for (int i = i0 + (int)threadIdx.x; i < iend; i += 256) {
    float2 x = *(float2*)(p + 2 * (size_t)i);
    float a = fmaf(x.x, scale, shift); a = fmaxf(a, 0.2f * a);
    float b = fmaf(x.y, scale, shift); b = fmaxf(b, 0.2f * b);
    *(float2*)(p + 2 * (size_t)i) = make_float2(a, b);
  }
}

extern "C" void kernel_launch(void* const* d_in, const int* in_sizes, int n_in,
                              void* d_out, int out_size, void* d_ws, size_t ws_size,
                              hipStream_t stream) {
  const float* x1   = (const float*)d_in[0];
  const float* x2   = (const float*)d_in[1];
  const int*   neigh= (const int*)d_in[2];
  const int*   top  = (const int*)d_in[3];
  const int*   down = (const int*)d_in[4];
  const float* Wup  = (const float*)d_in[5];
  const float* bup  = (const float*)d_in[6];
  const float* W1   = (const float*)d_in[7];
  // d_in[8] = b1: cancels exactly in BN -> skipped
  const float* g1   = (const float*)d_in[9];
  const float* be1  = (const float*)d_in[10];
  const float* W2   = (const float*)d_in[11];
  // d_in[12] = b2: cancels in BN -> skipped
  const float* g2   = (const float*)d_in[13];
  const float* be2  = (const float*)d_in[14];
  float* out = (float*)d_out;

  char* ws = (char*)d_ws;
  _Float16* rawq = (_Float16*)ws;                         //  73,403,904 B (dead after k_assemble)
  _Float16* y    = (_Float16*)(ws + 73403904);            //  83,887,104 B
  _Float16* t1   = (_Float16*)(ws + 157291008);           //  41,943,552 B
  float* stats   = (float*)(ws + 199234560);              //   4 KiB (sc/sh only)
  float* sc1 = stats;        float* sh1 = stats + 128;
  float* sc2 = stats + 256;  float* sh2 = stats + 384;
  // Overlays in the rawq region (dead after k_assemble):
  _Float16* WupP = t1;                                     // 28,672 B (t1 written later by conv1)
  _Float16* W1p  = rawq;                                   // 28,672 B
  _Float16* W2p  = rawq + 14336;                           // 14,336 B
  float* sumsR1 = (float*)(ws + (1 << 20));                // 64 reps x 256 f32 = 65,536 B
  float* sumsR2 = (float*)(ws + (1 << 20) + 65536);        // 65,536 B

  k_pack_up  <<<56, 256, 0, stream>>>(Wup, WupP);
  k_upconv   <<<dim3(641, Bn),  256, 0, stream>>>(x1, bup, WupP, rawq);
  k_assemble <<<dim3(641, Bn),  256, 0, stream>>>(x2, top, down, rawq, y);
  k_pack     <<<84, 256, 0, stream>>>(W1, W2, W1p, W2p);   // rawq dead from here
  hipMemsetAsync(sumsR1, 0, 131072, stream);               // zero both replica arrays
  k_conv1    <<<dim3(2561, Bn), 256, 0, stream>>>(y, neigh, W1p, t1, sumsR1);
  k_finalize <<<1, 128, 0, stream>>>(sumsR1, g1, be1, sc1, sh1);
  k_conv2    <<<dim3(2561, Bn), 256, 0, stream>>>(t1, neigh, W2p, sc1, sh1, out, sumsR2);
  k_finalize <<<1, 128, 0, stream>>>(sumsR2, g2, be2, sc2, sh2);
  k_bnorm    <<<dim3(4, 128),   256, 0, stream>>>(out, sc2, sh2);
}